// Round 12
// baseline (597.410 us; speedup 1.0000x reference)
//
#include <hip/hip_runtime.h>

typedef __attribute__((ext_vector_type(8))) short bf16x8;
typedef __attribute__((ext_vector_type(4))) float f32x4;

static constexpr int EN   = 524288;
static constexpr int NUE_ = 512;
static constexpr int NAP_ = 1024;
static constexpr int HID_ = 32;
static constexpr int OD_  = 60;
static constexpr int OC_  = 64;
static constexpr int NB_  = 256;
static constexpr int CH_  = EN / NB_;

__device__ __forceinline__ unsigned short f2bf(float x) {
  unsigned int u = __float_as_uint(x);
  return (unsigned short)((u + 0x7fffu + ((u >> 16) & 1u)) >> 16);  // RNE
}
__device__ __forceinline__ float bf2f(unsigned int u) {
  return __uint_as_float(u << 16);
}

// ---- phase 1: per-block histograms + local rank, PLUS (extra blocks)
// weight prep and input-node tables (independent work folded in) ----
__global__ __launch_bounds__(256)
void lhist2x(const int* __restrict__ up_dst, const int* __restrict__ dn_dst,
             int* __restrict__ bh_up, int* __restrict__ bh_dn,
             unsigned short* __restrict__ lr_up, unsigned short* __restrict__ lr_dn,
             const float* __restrict__ c3u_ew, const float* __restrict__ c3u_msg,
             const float* __restrict__ c3d_ew, const float* __restrict__ c3d_msg,
             unsigned short* __restrict__ we3u, unsigned short* __restrict__ wm3u,
             unsigned short* __restrict__ we3d, unsigned short* __restrict__ wm3d,
             const float* __restrict__ x_ue, const float* __restrict__ x_ap,
             const float* __restrict__ c1_ew, const float* __restrict__ c1_msg,
             const float* __restrict__ c1_ew_b, const float* __restrict__ c1_msg_b,
             const float* __restrict__ c2_ew, const float* __restrict__ c2_ew_b,
             float* __restrict__ Y1j, float* __restrict__ Y1i,
             float* __restrict__ Y1m, float* __restrict__ Y2i)
{
  __shared__ int h[NAP_];
  const int t = threadIdx.x;
  if (blockIdx.x >= 2 * NB_) {
    const int xb = blockIdx.x - 2 * NB_;
    if (xb < 48) {   // prep_w jobs
      const float* W; unsigned short* out; int NREAL, NPAD, i;
      if (xb < 16)      { W = c3u_ew;  out = we3u; NREAL = 60; NPAD = 64; i = xb * 256 + t; }
      else if (xb < 24) { W = c3u_msg; out = wm3u; NREAL = 32; NPAD = 32; i = (xb - 16) * 256 + t; }
      else if (xb < 40) { W = c3d_ew;  out = we3d; NREAL = 60; NPAD = 64; i = (xb - 24) * 256 + t; }
      else              { W = c3d_msg; out = wm3d; NREAL = 32; NPAD = 32; i = (xb - 40) * 256 + t; }
      if (i >= NPAD * 64) return;
      int n = i >> 6, k = i & 63;
      float v = (n < NREAL) ? W[(size_t)(64 + k) * NREAL + n] : 0.f;
      out[i] = f2bf(v);
    } else {        // tabs0 jobs (8 blocks)
      const int tid = (xb - 48) * 256 + t;
      if (tid < NUE_) {
        const float4 x = *reinterpret_cast<const float4*>(x_ue + (size_t)tid * 4);
        const float xv[4] = {x.x, x.y, x.z, x.w};
        for (int o = 0; o < OD_; ++o) {
          float a = 0.f, bb = c2_ew_b[o];
          #pragma unroll
          for (int k = 0; k < 4; ++k) {
            a = fmaf(xv[k], c1_ew[k * OD_ + o], a);
            bb = fmaf(xv[k], c2_ew[(68 + k) * OD_ + o], bb);
          }
          Y1j[(size_t)tid * OD_ + o] = a;
          Y2i[(size_t)tid * OD_ + o] = bb;
        }
        for (int o = 0; o < HID_; ++o) {
          float m = c1_msg_b[o];
          #pragma unroll
          for (int k = 0; k < 4; ++k) m = fmaf(xv[k], c1_msg[k * HID_ + o], m);
          Y1m[(size_t)tid * HID_ + o] = m;
        }
      } else if (tid < NUE_ + NAP_) {
        const int r = tid - NUE_;
        const float4 x = *reinterpret_cast<const float4*>(x_ap + (size_t)r * 4);
        const float xv[4] = {x.x, x.y, x.z, x.w};
        for (int o = 0; o < OD_; ++o) {
          float a = c1_ew_b[o];
          #pragma unroll
          for (int k = 0; k < 4; ++k) a = fmaf(xv[k], c1_ew[(8 + k) * OD_ + o], a);
          Y1i[(size_t)r * OD_ + o] = a;
        }
      }
    }
    return;
  }
  const bool up = blockIdx.x < NB_;
  const int b = up ? blockIdx.x : blockIdx.x - NB_;
  const int NBINS = up ? NAP_ : NUE_;
  const int* dst = up ? up_dst : dn_dst;
  int* bh = up ? bh_up : bh_dn;
  unsigned short* lrank = up ? lr_up : lr_dn;
  for (int i = t; i < NBINS; i += 256) h[i] = 0;
  __syncthreads();
  const int base = b * CH_;
  #pragma unroll 1
  for (int i = t; i < CH_; i += 256)
    lrank[base + i] = (unsigned short)atomicAdd(&h[dst[base + i]], 1);
  __syncthreads();
  for (int i = t; i < NBINS; i += 256)
    bh[(size_t)i * NB_ + b] = h[i];
}

__global__ __launch_bounds__(64)
void bscanA2(int* __restrict__ bh_up, int* __restrict__ bh_dn,
             int* __restrict__ bs_up, int* __restrict__ bs_dn)
{
  const bool up = blockIdx.x < NAP_;
  const int bin = up ? blockIdx.x : blockIdx.x - NAP_;
  int* bh = up ? bh_up : bh_dn;
  int* binsum = up ? bs_up : bs_dn;
  const int l = threadIdx.x;
  int4 v = *reinterpret_cast<int4*>(&bh[(size_t)bin * NB_ + l * 4]);
  const int s0 = v.x, s1 = s0 + v.y, s2 = s1 + v.z, s3 = s2 + v.w;
  int inc = s3;
  #pragma unroll
  for (int d2 = 1; d2 < 64; d2 <<= 1) {
    int n = __shfl_up(inc, d2, 64);
    if (l >= d2) inc += n;
  }
  const int exc = inc - s3;
  int4 o; o.x = exc; o.y = exc + s0; o.z = exc + s1; o.w = exc + s2;
  *reinterpret_cast<int4*>(&bh[(size_t)bin * NB_ + l * 4]) = o;
  if (l == 63) binsum[bin] = inc;
}

__global__ __launch_bounds__(256)
void bscanB2(const int* __restrict__ bs_up, int* __restrict__ off_up,
             const int* __restrict__ bs_dn, int* __restrict__ off_dn)
{
  const bool up = blockIdx.x == 0;
  const int NBINS = up ? NAP_ : NUE_;
  const int K = NBINS / 256;
  const int* binsum = up ? bs_up : bs_dn;
  int* off = up ? off_up : off_dn;
  __shared__ int wtot[4];
  const int t = threadIdx.x, lane = t & 63, wid = t >> 6;
  int loc[4]; int s = 0;
  for (int k = 0; k < K; ++k) { loc[k] = binsum[t * K + k]; s += loc[k]; }
  int inc = s;
  #pragma unroll
  for (int d2 = 1; d2 < 64; d2 <<= 1) {
    int n = __shfl_up(inc, d2, 64);
    if (lane >= d2) inc += n;
  }
  if (lane == 63) wtot[wid] = inc;
  __syncthreads();
  int woff = 0;
  #pragma unroll
  for (int ww = 0; ww < 4; ++ww) if (ww < wid) woff += wtot[ww];
  int a = woff + inc - s;
  for (int k = 0; k < K; ++k) { off[t * K + k] = a; a += loc[k]; }
  if (t == 255) off[NBINS] = a;
}

__global__ __launch_bounds__(256)
void rankc2(const int* __restrict__ up_dst, const int* __restrict__ up_src,
            const int* __restrict__ dn_dst, const int* __restrict__ dn_src,
            const unsigned short* __restrict__ lr_up, const unsigned short* __restrict__ lr_dn,
            const int* __restrict__ bh_up, const int* __restrict__ bh_dn,
            const int* __restrict__ off_up, const int* __restrict__ off_dn,
            int* __restrict__ rank_dn,
            int* __restrict__ perm_up, int* __restrict__ srcP_up, int* __restrict__ dstP_up,
            int* __restrict__ perm_dn, int* __restrict__ srcP_dn, int* __restrict__ dstP_dn)
{
  const int gid = blockIdx.x * 256 + threadIdx.x;
  const bool up = gid < EN;
  const int e = up ? gid : gid - EN;
  const int* dst = up ? up_dst : dn_dst;
  const int* src = up ? up_src : dn_src;
  const unsigned short* lrank = up ? lr_up : lr_dn;
  const int* bh = up ? bh_up : bh_dn;
  const int* off = up ? off_up : off_dn;
  const int blk = e / CH_;
  const int d = dst[e];
  const int rk = off[d] + bh[(size_t)d * NB_ + blk] + (int)lrank[e];
  if (up) {
    perm_up[rk] = e; srcP_up[rk] = src[e]; dstP_up[rk] = d;
  } else {
    rank_dn[e] = rk;
    perm_dn[rk] = e; srcP_dn[rk] = src[e]; dstP_dn[rk] = d;
  }
}

// ---- fused conv1/conv2: edge stage + node update + next-conv tables ----
// Block = one dst node; streams its contiguous slot segment. 4 thr/edge.
__global__ __launch_bounds__(256)
void e12n(const float* __restrict__ ea_in,
          const int* __restrict__ perm, const int* __restrict__ srcP,
          const int* __restrict__ off,
          const float* __restrict__ Yje, const float* __restrict__ Yie,
          const float* __restrict__ Ym,
          const float* __restrict__ We,   // 4x60 (ea rows of ew_W)
          const float* __restrict__ Wm,   // 4x32
          unsigned short* __restrict__ outB,    // [E][64] bf16 mirror, slot order
          const float* __restrict__ x_in,       // [N][4]
          const float* __restrict__ W, const float* __restrict__ b,
          float* __restrict__ x_out,
          const float* __restrict__ WtA, float* __restrict__ YA,
          const float* __restrict__ WtB, const float* __restrict__ bB, float* __restrict__ YB,
          const float* __restrict__ WtC, const float* __restrict__ bC, float* __restrict__ YC)
{
  __shared__ unsigned short Eb[64 * 72];
  __shared__ float RedF[64][33];
  __shared__ float Part[8][33];
  __shared__ float Ag[32];
  __shared__ float Xr[4];
  __shared__ float Xn[OC_];
  const int d = blockIdx.x, t = threadIdx.x;
  const int beg = off[d], end = off[d + 1];
  const int r = t >> 2, j = t & 3;
  const int c0 = j * 15, m0 = j * 8;
  if (t < 4) Xr[t] = x_in[(size_t)d * 4 + t];
  float yie[15];
  #pragma unroll
  for (int c = 0; c < 15; ++c) yie[c] = Yie[(size_t)d * OD_ + c0 + c];
  float am[8] = {0.f, 0.f, 0.f, 0.f, 0.f, 0.f, 0.f, 0.f};

  for (int sb = beg; sb < end; sb += 64) {
    const int slot = sb + r;
    const bool act = slot < end;
    const int e = act ? perm[slot] : 0;
    const int s = act ? srcP[slot] : 0;
    float4 ea = act ? *reinterpret_cast<const float4*>(ea_in + (size_t)e * 4)
                    : make_float4(0.f, 0.f, 0.f, 0.f);
    const float eav[4] = {ea.x, ea.y, ea.z, ea.w};
    // ew cols [c0, c0+15)
    float acc[15];
    #pragma unroll
    for (int c = 0; c < 15; ++c) acc[c] = Yje[(size_t)s * OD_ + c0 + c] + yie[c];
    #pragma unroll
    for (int k = 0; k < 4; ++k)
      #pragma unroll
      for (int c = 0; c < 15; ++c)
        acc[c] = fmaf(eav[k], We[k * OD_ + c0 + c], acc[c]);
    if (act) {
      #pragma unroll
      for (int c = 0; c < 15; ++c) {
        float v = acc[c] >= 0.f ? acc[c] : 0.1f * acc[c];
        Eb[r * 72 + 4 + c0 + c] = f2bf(v);
      }
      if (j == 0) {
        Eb[r * 72 + 0] = f2bf(ea.x); Eb[r * 72 + 1] = f2bf(ea.y);
        Eb[r * 72 + 2] = f2bf(ea.z); Eb[r * 72 + 3] = f2bf(ea.w);
      }
    }
    // msg cols [m0, m0+8), accumulate in fp32 registers
    float m[8];
    #pragma unroll
    for (int c = 0; c < 8; ++c) m[c] = Ym[(size_t)s * HID_ + m0 + c];
    #pragma unroll
    for (int k = 0; k < 4; ++k)
      #pragma unroll
      for (int c = 0; c < 8; ++c)
        m[c] = fmaf(eav[k], Wm[k * HID_ + m0 + c], m[c]);
    if (act) {
      #pragma unroll
      for (int c = 0; c < 8; ++c)
        am[c] += m[c] >= 0.f ? m[c] : 0.1f * m[c];
    }
    __syncthreads();
    const int nact = end - sb < 64 ? end - sb : 64;
    for (int idx = t; idx < nact * 8; idx += 256) {
      int row = idx >> 3, ch = idx & 7;
      *reinterpret_cast<uint4*>(outB + (size_t)(sb + row) * OC_ + ch * 8) =
          *reinterpret_cast<const uint4*>(&Eb[row * 72 + ch * 8]);
    }
    __syncthreads();
  }
  // reduce am over the block: RedF[r][m0+c] -> Part[8][32] -> Ag[32]
  #pragma unroll
  for (int c = 0; c < 8; ++c) RedF[r][m0 + c] = am[c];
  __syncthreads();
  {
    const int col = t & 31, g = t >> 5;
    float s = 0.f;
    #pragma unroll
    for (int r2 = 0; r2 < 8; ++r2) s += RedF[g * 8 + r2][col];
    Part[g][col] = s;
  }
  __syncthreads();
  if (t < 32) {
    float s = 0.f;
    #pragma unroll
    for (int g2 = 0; g2 < 8; ++g2) s += Part[g2][t];
    Ag[t] = s;
  }
  __syncthreads();
  // node update (LX=4, no residual)
  if (t < OD_) {
    float acc = b[t];
    #pragma unroll
    for (int k = 0; k < 4; ++k) acc = fmaf(Xr[k], W[k * OD_ + t], acc);
    #pragma unroll 4
    for (int k = 0; k < HID_; ++k) acc = fmaf(Ag[k], W[(4 + k) * OD_ + t], acc);
    acc = acc >= 0.f ? acc : 0.1f * acc;
    x_out[(size_t)d * OC_ + 4 + t] = acc;
    Xn[4 + t] = acc;
  } else if (t < OC_) {
    x_out[(size_t)d * OC_ + (t - OD_)] = Xr[t - OD_];
    Xn[t - OD_] = Xr[t - OD_];
  }
  __syncthreads();
  if (t < OD_) {
    float a = 0.f;
    #pragma unroll 4
    for (int k = 0; k < OC_; ++k) a = fmaf(Xn[k], WtA[k * OD_ + t], a);
    YA[(size_t)d * OD_ + t] = a;
  } else if (t >= 64 && t < 96) {
    const int cc = t - 64;
    float a = bB[cc];
    #pragma unroll 4
    for (int k = 0; k < OC_; ++k) a = fmaf(Xn[k], WtB[k * HID_ + cc], a);
    YB[(size_t)d * HID_ + cc] = a;
  } else if (t >= 128 && t < 188) {
    const int cc = t - 128;
    float a = bC[cc];
    #pragma unroll 4
    for (int k = 0; k < OC_; ++k) a = fmaf(Xn[k], WtC[k * OD_ + cc], a);
    YC[(size_t)d * OD_ + cc] = a;
  }
}

// conv3 edge stage, slot order; A fragments for all 4 tiles loaded upfront.
template<bool FUSE>
__global__ __launch_bounds__(256)
void edge3(const unsigned short* __restrict__ eaB,
           const float* __restrict__ ea0_src,
           const int* __restrict__ perm,
           const int* __restrict__ srcP, const int* __restrict__ dstP,
           const unsigned short* __restrict__ Wet, const unsigned short* __restrict__ Wmt,
           const float* __restrict__ Yje, const float* __restrict__ Yie,
           const float* __restrict__ Ym,
           unsigned int* __restrict__ msg32,
           float* __restrict__ ea_out,
           float* __restrict__ pT,
           const float* __restrict__ pe1_W)
{
  const int t = threadIdx.x, l = t & 63, w = t >> 6;
  const int lr = l & 15, lkb = l >> 4;
  const int sW = blockIdx.x * 256 + w * 64;

  // all 4 A-tiles upfront (contiguous mirror) for deep ILP
  bf16x8 a[4][2];
  #pragma unroll
  for (int tile = 0; tile < 4; ++tile) {
    const unsigned short* ar = eaB + (size_t)(sW + tile * 16 + lr) * OC_ + lkb * 8;
    a[tile][0] = *reinterpret_cast<const bf16x8*>(ar);
    a[tile][1] = *reinterpret_cast<const bf16x8*>(ar + 32);
  }
  bf16x8 be[4][2], bm[2][2];
  #pragma unroll
  for (int nt = 0; nt < 4; ++nt)
    #pragma unroll
    for (int kk = 0; kk < 2; ++kk)
      be[nt][kk] = *reinterpret_cast<const bf16x8*>(Wet + (nt * 16 + lr) * 64 + kk * 32 + lkb * 8);
  #pragma unroll
  for (int nt = 0; nt < 2; ++nt)
    #pragma unroll
    for (int kk = 0; kk < 2; ++kk)
      bm[nt][kk] = *reinterpret_cast<const bf16x8*>(Wmt + (nt * 16 + lr) * 64 + kk * 32 + lkb * 8);

  #pragma unroll 1
  for (int tile = 0; tile < 4; ++tile) {
    const int s0t = sW + tile * 16;
    // issue s/d loads before MFMA so gather latency hides under matrix ops
    int sA[4], dA[4];
    #pragma unroll
    for (int r = 0; r < 4; ++r) {
      sA[r] = srcP[s0t + lkb * 4 + r];
      dA[r] = dstP[s0t + lkb * 4 + r];
    }
    f32x4 accE[4] = {f32x4{0,0,0,0}, f32x4{0,0,0,0}, f32x4{0,0,0,0}, f32x4{0,0,0,0}};
    f32x4 accM[2] = {f32x4{0,0,0,0}, f32x4{0,0,0,0}};
    #pragma unroll
    for (int kk = 0; kk < 2; ++kk) {
      #pragma unroll
      for (int nt = 0; nt < 4; ++nt)
        accE[nt] = __builtin_amdgcn_mfma_f32_16x16x32_bf16(a[tile][kk], be[nt][kk], accE[nt], 0, 0, 0);
      #pragma unroll
      for (int nt = 0; nt < 2; ++nt)
        accM[nt] = __builtin_amdgcn_mfma_f32_16x16x32_bf16(a[tile][kk], bm[nt][kk], accM[nt], 0, 0, 0);
    }
    #pragma unroll
    for (int r = 0; r < 4; ++r) {
      const int sl = s0t + lkb * 4 + r;
      const int s = sA[r], d = dA[r];
      float v0 = accM[0][r] + Ym[(size_t)s * HID_ + lr];
      float v1 = accM[1][r] + Ym[(size_t)s * HID_ + 16 + lr];
      v0 = v0 >= 0.f ? v0 : 0.1f * v0;
      v1 = v1 >= 0.f ? v1 : 0.1f * v1;
      const int q0 = (2 * lr) & 15, q1 = (2 * lr + 1) & 15;
      float t00 = __shfl(v0, q0, 16), t10 = __shfl(v1, q0, 16);
      float t01 = __shfl(v0, q1, 16), t11 = __shfl(v1, q1, 16);
      float lo = (lr < 8) ? t00 : t10;
      float hi = (lr < 8) ? t01 : t11;
      msg32[(size_t)sl * 16 + lr] = ((unsigned)f2bf(hi) << 16) | f2bf(lo);

      float val[4];
      #pragma unroll
      for (int nt = 0; nt < 4; ++nt) {
        int col = nt * 16 + lr;
        float v = (col < OD_)
            ? accE[nt][r] + Yje[(size_t)s * OD_ + col] + Yie[(size_t)d * OD_ + col]
            : 0.f;
        val[nt] = v >= 0.f ? v : 0.1f * v;
      }
      if constexpr (!FUSE) {
        const int e = perm[sl];
        #pragma unroll
        for (int nt = 0; nt < 4; ++nt) {
          int col = nt * 16 + lr;
          if (col < OD_) ea_out[(size_t)e * OC_ + 4 + col] = val[nt];
        }
        if (lr == 0) {
          float4 ea0 = *reinterpret_cast<const float4*>(ea0_src + (size_t)e * 4);
          *reinterpret_cast<float4*>(ea_out + (size_t)e * OC_) = ea0;
        }
      } else {
        float p4[4] = {0.f, 0.f, 0.f, 0.f};
        #pragma unroll
        for (int nt = 0; nt < 4; ++nt) {
          int col = nt * 16 + lr;
          if (col < OD_) {
            #pragma unroll
            for (int jj = 0; jj < 4; ++jj)
              p4[jj] = fmaf(val[nt], pe1_W[(4 + col) * 4 + jj], p4[jj]);
          }
        }
        #pragma unroll
        for (int mk = 1; mk < 16; mk <<= 1) {
          #pragma unroll
          for (int jj = 0; jj < 4; ++jj)
            p4[jj] += __shfl_xor(p4[jj], mk, 64);
        }
        if (lr == 0)
          *reinterpret_cast<float4*>(pT + (size_t)sl * 4) =
              make_float4(p4[0], p4[1], p4[2], p4[3]);
      }
    }
  }
}

// ---- node update for conv3 (+ optional table build) ----
template<int LX, bool RES>
__device__ __forceinline__
void nodeup_body(int d, int t,
                 const float* __restrict__ x_in,
                 const unsigned int* __restrict__ msg32,
                 const int* __restrict__ off,
                 const float* __restrict__ W, const float* __restrict__ b,
                 float* __restrict__ x_out,
                 const float* WtA, float* YA,
                 const float* WtB, const float* bB, float* YB)
{
  __shared__ float Pb[16][32];
  __shared__ float Ag[32];
  __shared__ float Xr[LX];
  __shared__ float Xn[OC_];
  const int beg = off[d], end = off[d + 1];
  const int c = t & 15, g = t >> 4;
  float px = 0.f, py = 0.f;
  for (int i = beg + g; i < end; i += 16) {
    unsigned u = msg32[(size_t)i * 16 + c];
    px += bf2f(u & 0xffffu);
    py += bf2f(u >> 16);
  }
  Pb[g][2 * c] = px; Pb[g][2 * c + 1] = py;
  if (t < LX) Xr[t] = x_in[(size_t)d * LX + t];
  __syncthreads();
  if (t < 32) {
    float s = 0.f;
    #pragma unroll
    for (int g2 = 0; g2 < 16; ++g2) s += Pb[g2][t];
    Ag[t] = s;
  }
  __syncthreads();
  if (t < OD_) {
    float acc = b[t];
    #pragma unroll 4
    for (int k = 0; k < LX; ++k) acc = fmaf(Xr[k], W[k * OD_ + t], acc);
    #pragma unroll 4
    for (int k = 0; k < HID_; ++k) acc = fmaf(Ag[k], W[(LX + k) * OD_ + t], acc);
    acc = acc >= 0.f ? acc : 0.1f * acc;
    if constexpr (RES) acc += Xr[4 + t];
    x_out[(size_t)d * OC_ + 4 + t] = acc;
    Xn[4 + t] = acc;
  } else if (t < OC_) {
    x_out[(size_t)d * OC_ + (t - OD_)] = Xr[t - OD_];
    Xn[t - OD_] = Xr[t - OD_];
  }
  if (WtA == nullptr) return;
  __syncthreads();
  if (t < OD_) {
    float a = 0.f;
    #pragma unroll 4
    for (int k = 0; k < OC_; ++k) a = fmaf(Xn[k], WtA[k * OD_ + t], a);
    YA[(size_t)d * OD_ + t] = a;
  } else if (t >= 64 && t < 96) {
    const int cc = t - 64;
    float a = bB[cc];
    #pragma unroll 4
    for (int k = 0; k < OC_; ++k) a = fmaf(Xn[k], WtB[k * HID_ + cc], a);
    YB[(size_t)d * HID_ + cc] = a;
  }
}

template<int LX, bool RES>
__global__ __launch_bounds__(256)
void nodeupT(const float* __restrict__ x_in, const unsigned int* __restrict__ msg32,
             const int* __restrict__ off,
             const float* __restrict__ W, const float* __restrict__ b,
             float* __restrict__ x_out,
             const float* WtA, float* YA,
             const float* WtB, const float* bB, float* YB)
{
  nodeup_body<LX, RES>(blockIdx.x, threadIdx.x, x_in, msg32, off, W, b, x_out,
                       WtA, YA, WtB, bB, YB);
}

// final: nodeup(conv3d, UE) blocks [0,512) + powout blocks [512, 512+2048)
__global__ __launch_bounds__(256)
void nodeup_pow(const float* __restrict__ x_in, const unsigned int* __restrict__ msg32,
                const int* __restrict__ off,
                const float* __restrict__ W, const float* __restrict__ b,
                float* __restrict__ x_out,
                const float* __restrict__ ea0_src, const int* __restrict__ rank,
                const float* __restrict__ pT,
                const float* __restrict__ pe1_W, const float* __restrict__ pe1_b,
                const float* __restrict__ pe2_W, const float* __restrict__ pe2_b,
                const float* __restrict__ ln_g, const float* __restrict__ ln_b,
                float* __restrict__ outp)
{
  if (blockIdx.x < NUE_) {
    nodeup_body<OC_, true>(blockIdx.x, threadIdx.x, x_in, msg32, off, W, b, x_out,
                           nullptr, nullptr, nullptr, nullptr, nullptr);
    return;
  }
  const int e = (blockIdx.x - NUE_) * 256 + threadIdx.x;
  const int rk = rank[e];
  const float4 p4 = *reinterpret_cast<const float4*>(pT + (size_t)rk * 4);
  const float4 ea0 = *reinterpret_cast<const float4*>(ea0_src + (size_t)e * 4);
  const float pv[4] = {p4.x, p4.y, p4.z, p4.w};
  float v4[4];
  #pragma unroll
  for (int jj = 0; jj < 4; ++jj)
    v4[jj] = pv[jj] + pe1_b[jj]
           + ea0.x * pe1_W[0 * 4 + jj] + ea0.y * pe1_W[1 * 4 + jj]
           + ea0.z * pe1_W[2 * 4 + jj] + ea0.w * pe1_W[3 * 4 + jj];
  const float mu = 0.25f * (v4[0] + v4[1] + v4[2] + v4[3]);
  float var = 0.f;
  #pragma unroll
  for (int jj = 0; jj < 4; ++jj) { float dd = v4[jj] - mu; var = fmaf(dd, dd, var); }
  var *= 0.25f;
  const float rstd = rsqrtf(var + 1e-5f);
  float p = pe2_b[0];
  #pragma unroll
  for (int jj = 0; jj < 4; ++jj) {
    float h = (v4[jj] - mu) * rstd * ln_g[jj] + ln_b[jj];
    h = h >= 0.f ? h : 0.1f * h;
    p = fmaf(h, pe2_W[jj], p);
  }
  float* orow = outp + (size_t)e * 5;
  orow[0] = ea0.x; orow[1] = ea0.y; orow[2] = ea0.z; orow[3] = ea0.w;
  orow[4] = p;
}

extern "C" void kernel_launch(void* const* d_in, const int* in_sizes, int n_in,
                              void* d_out, int out_size, void* d_ws, size_t ws_size,
                              hipStream_t stream)
{
  const float* x_ue    = (const float*)d_in[0];
  const float* x_ap    = (const float*)d_in[1];
  const float* ea_up   = (const float*)d_in[2];
  const float* ea_down = (const float*)d_in[3];
  const int* up_src = (const int*)d_in[4];
  const int* up_dst = (const int*)d_in[5];
  const int* dn_src = (const int*)d_in[6];
  const int* dn_dst = (const int*)d_in[7];
  const float* c1_msg_W = (const float*)d_in[8];  const float* c1_msg_b = (const float*)d_in[9];
  const float* c1_upd_W = (const float*)d_in[10]; const float* c1_upd_b = (const float*)d_in[11];
  const float* c1_ew_W  = (const float*)d_in[12]; const float* c1_ew_b  = (const float*)d_in[13];
  const float* c2_msg_W = (const float*)d_in[14]; const float* c2_msg_b = (const float*)d_in[15];
  const float* c2_upd_W = (const float*)d_in[16]; const float* c2_upd_b = (const float*)d_in[17];
  const float* c2_ew_W  = (const float*)d_in[18]; const float* c2_ew_b  = (const float*)d_in[19];
  const float* c3u_msg_W= (const float*)d_in[20]; const float* c3u_msg_b= (const float*)d_in[21];
  const float* c3u_upd_W= (const float*)d_in[22]; const float* c3u_upd_b= (const float*)d_in[23];
  const float* c3u_ew_W = (const float*)d_in[24]; const float* c3u_ew_b = (const float*)d_in[25];
  const float* c3d_msg_W= (const float*)d_in[26]; const float* c3d_msg_b= (const float*)d_in[27];
  const float* c3d_upd_W= (const float*)d_in[28]; const float* c3d_upd_b= (const float*)d_in[29];
  const float* c3d_ew_W = (const float*)d_in[30]; const float* c3d_ew_b = (const float*)d_in[31];
  const float* pe1_W = (const float*)d_in[32]; const float* pe1_b = (const float*)d_in[33];
  const float* pe2_W = (const float*)d_in[34]; const float* pe2_b = (const float*)d_in[35];
  const float* ln_g  = (const float*)d_in[36]; const float* ln_b  = (const float*)d_in[37];

  float* out    = (float*)d_out;
  float* x_ue_o = out;
  float* x_ap_o = out + (size_t)NUE_ * OC_;
  float* ea_up_o = x_ap_o + (size_t)NAP_ * OC_;
  float* ea_dn_o = ea_up_o + (size_t)EN * OC_;

  // ---- workspace layout ----
  int* ip = (int*)d_ws;
  int* rank_dn = ip; ip += EN;
  int* perm_up = ip; ip += EN;
  int* src_upP = ip; ip += EN;
  int* dst_upP = ip; ip += EN;
  int* perm_dn = ip; ip += EN;
  int* src_dnP = ip; ip += EN;
  int* dst_dnP = ip; ip += EN;
  int* bh_up   = ip; ip += NAP_ * NB_;
  int* bh_dn   = ip; ip += NUE_ * NB_;
  int* off_up  = ip; ip += NAP_ + 1;
  int* off_dn  = ip; ip += NUE_ + 1;
  int* bs_up   = ip; ip += NAP_;
  int* bs_dn   = ip; ip += NUE_;
  unsigned short* lr_up = (unsigned short*)ip; ip += EN / 2;
  unsigned short* lr_dn = (unsigned short*)ip; ip += EN / 2;
  float* p = (float*)ip;
  float* Y1j = p;  p += NUE_ * OD_;  float* Y1i = p; p += NAP_ * OD_;  float* Y1m = p; p += NUE_ * HID_;
  float* Y2j = p;  p += NAP_ * OD_;  float* Y2i = p; p += NUE_ * OD_;  float* Y2m = p; p += NAP_ * HID_;
  float* Y3uj = p; p += NUE_ * OD_;  float* Y3ui = p; p += NAP_ * OD_; float* Y3um = p; p += NUE_ * HID_;
  float* Y3dj = p; p += NAP_ * OD_;  float* Y3di = p; p += NUE_ * OD_; float* Y3dm = p; p += NAP_ * HID_;
  float* pT = p;   p += (size_t)EN * 4;
  unsigned short* us = (unsigned short*)p;
  unsigned short* ea_up_bf = us;  us += (size_t)EN * OC_;
  unsigned short* ea_dn_bf = us;  us += (size_t)EN * OC_;
  unsigned short* we3u = us; us += 64 * 64;
  unsigned short* wm3u = us; us += 32 * 64;
  unsigned short* we3d = us; us += 64 * 64;
  unsigned short* wm3d = us; us += 32 * 64;
  unsigned int* msg32 = (unsigned int*)(((size_t)us + 15) & ~(size_t)15);

  const dim3 blk(256);
  const dim3 ege(EN / 256);        // 2048

  // phase 1: histograms + (folded) weight prep + input tables
  lhist2x<<<dim3(2 * NB_ + 56), blk, 0, stream>>>(
      up_dst, dn_dst, bh_up, bh_dn, lr_up, lr_dn,
      c3u_ew_W, c3u_msg_W, c3d_ew_W, c3d_msg_W, we3u, wm3u, we3d, wm3d,
      x_ue, x_ap, c1_ew_W, c1_msg_W, c1_ew_b, c1_msg_b, c2_ew_W, c2_ew_b,
      Y1j, Y1i, Y1m, Y2i);
  bscanA2<<<dim3(NAP_ + NUE_), dim3(64), 0, stream>>>(bh_up, bh_dn, bs_up, bs_dn);
  bscanB2<<<dim3(2), blk, 0, stream>>>(bs_up, off_up, bs_dn, off_dn);
  rankc2<<<dim3(2 * EN / 256), blk, 0, stream>>>(
      up_dst, up_src, dn_dst, dn_src, lr_up, lr_dn, bh_up, bh_dn, off_up, off_dn,
      rank_dn, perm_up, src_upP, dst_upP, perm_dn, src_dnP, dst_dnP);

  // conv1 (fused edge+node): builds Y2j/Y2m + Y3ui
  e12n<<<dim3(NAP_), blk, 0, stream>>>(
      ea_up, perm_up, src_upP, off_up, Y1j, Y1i, Y1m,
      c1_ew_W + 4 * OD_, c1_msg_W + 4 * HID_, ea_up_bf,
      x_ap, c1_upd_W, c1_upd_b, x_ap_o,
      c2_ew_W, Y2j, c2_msg_W, c2_msg_b, Y2m,
      c3u_ew_W + 128 * OD_, c3u_ew_b, Y3ui);

  // conv2 (fused edge+node): builds Y3uj/Y3um + Y3di
  e12n<<<dim3(NUE_), blk, 0, stream>>>(
      ea_down, perm_dn, src_dnP, off_dn, Y2j, Y2i, Y2m,
      c2_ew_W + 64 * OD_, c2_msg_W + 64 * HID_, ea_dn_bf,
      x_ue, c2_upd_W, c2_upd_b, x_ue_o,
      c3u_ew_W, Y3uj, c3u_msg_W, c3u_msg_b, Y3um,
      c3d_ew_W + 128 * OD_, c3d_ew_b, Y3di);

  // conv3u: edge GEMM then node update (+Y3dj/Y3dm tables)
  edge3<false><<<ege, blk, 0, stream>>>(
      ea_up_bf, ea_up, perm_up, src_upP, dst_upP, we3u, wm3u,
      Y3uj, Y3ui, Y3um, msg32, ea_up_o, nullptr, nullptr);
  nodeupT<64, true><<<dim3(NAP_), blk, 0, stream>>>(
      x_ap_o, msg32, off_up, c3u_upd_W, c3u_upd_b, x_ap_o,
      c3d_ew_W, Y3dj, c3d_msg_W, c3d_msg_b, Y3dm);

  // conv3d: edge GEMM -> pT, then merged nodeup+powout
  edge3<true><<<ege, blk, 0, stream>>>(
      ea_dn_bf, nullptr, nullptr, src_dnP, dst_dnP, we3d, wm3d,
      Y3dj, Y3di, Y3dm, msg32, nullptr, pT, pe1_W);
  nodeup_pow<<<dim3(NUE_ + EN / 256), blk, 0, stream>>>(
      x_ue_o, msg32, off_dn, c3d_upd_W, c3d_upd_b, x_ue_o,
      ea_down, rank_dn, pT, pe1_W, pe1_b, pe2_W, pe2_b, ln_g, ln_b, ea_dn_o);
}

// Round 13
// 432.000 us; speedup vs baseline: 1.3829x; 1.3829x over previous
//
#include <hip/hip_runtime.h>

typedef __attribute__((ext_vector_type(8))) short bf16x8;
typedef __attribute__((ext_vector_type(4))) float f32x4;

static constexpr int EN   = 524288;
static constexpr int NUE_ = 512;
static constexpr int NAP_ = 1024;
static constexpr int HID_ = 32;
static constexpr int OD_  = 60;
static constexpr int OC_  = 64;
static constexpr int NB_  = 256;
static constexpr int CH_  = EN / NB_;

__device__ __forceinline__ unsigned short f2bf(float x) {
  unsigned int u = __float_as_uint(x);
  return (unsigned short)((u + 0x7fffu + ((u >> 16) & 1u)) >> 16);  // RNE
}
__device__ __forceinline__ float bf2f(unsigned int u) {
  return __uint_as_float(u << 16);
}

// ---- phase 1: per-block histograms + local rank, PLUS (extra blocks)
// weight prep and input-node tables (independent work folded in) ----
__global__ __launch_bounds__(256)
void lhist2x(const int* __restrict__ up_dst, const int* __restrict__ dn_dst,
             int* __restrict__ bh_up, int* __restrict__ bh_dn,
             unsigned short* __restrict__ lr_up, unsigned short* __restrict__ lr_dn,
             const float* __restrict__ c3u_ew, const float* __restrict__ c3u_msg,
             const float* __restrict__ c3d_ew, const float* __restrict__ c3d_msg,
             unsigned short* __restrict__ we3u, unsigned short* __restrict__ wm3u,
             unsigned short* __restrict__ we3d, unsigned short* __restrict__ wm3d,
             const float* __restrict__ x_ue, const float* __restrict__ x_ap,
             const float* __restrict__ c1_ew, const float* __restrict__ c1_msg,
             const float* __restrict__ c1_ew_b, const float* __restrict__ c1_msg_b,
             const float* __restrict__ c2_ew, const float* __restrict__ c2_ew_b,
             float* __restrict__ Y1j, float* __restrict__ Y1i,
             float* __restrict__ Y1m, float* __restrict__ Y2i)
{
  __shared__ int h[NAP_];
  const int t = threadIdx.x;
  if (blockIdx.x >= 2 * NB_) {
    const int xb = blockIdx.x - 2 * NB_;
    if (xb < 48) {   // prep_w jobs
      const float* W; unsigned short* out; int NREAL, NPAD, i;
      if (xb < 16)      { W = c3u_ew;  out = we3u; NREAL = 60; NPAD = 64; i = xb * 256 + t; }
      else if (xb < 24) { W = c3u_msg; out = wm3u; NREAL = 32; NPAD = 32; i = (xb - 16) * 256 + t; }
      else if (xb < 40) { W = c3d_ew;  out = we3d; NREAL = 60; NPAD = 64; i = (xb - 24) * 256 + t; }
      else              { W = c3d_msg; out = wm3d; NREAL = 32; NPAD = 32; i = (xb - 40) * 256 + t; }
      if (i >= NPAD * 64) return;
      int n = i >> 6, k = i & 63;
      float v = (n < NREAL) ? W[(size_t)(64 + k) * NREAL + n] : 0.f;
      out[i] = f2bf(v);
    } else {        // tabs0 jobs (8 blocks)
      const int tid = (xb - 48) * 256 + t;
      if (tid < NUE_) {
        const float4 x = *reinterpret_cast<const float4*>(x_ue + (size_t)tid * 4);
        const float xv[4] = {x.x, x.y, x.z, x.w};
        for (int o = 0; o < OD_; ++o) {
          float a = 0.f, bb = c2_ew_b[o];
          #pragma unroll
          for (int k = 0; k < 4; ++k) {
            a = fmaf(xv[k], c1_ew[k * OD_ + o], a);
            bb = fmaf(xv[k], c2_ew[(68 + k) * OD_ + o], bb);
          }
          Y1j[(size_t)tid * OD_ + o] = a;
          Y2i[(size_t)tid * OD_ + o] = bb;
        }
        for (int o = 0; o < HID_; ++o) {
          float m = c1_msg_b[o];
          #pragma unroll
          for (int k = 0; k < 4; ++k) m = fmaf(xv[k], c1_msg[k * HID_ + o], m);
          Y1m[(size_t)tid * HID_ + o] = m;
        }
      } else if (tid < NUE_ + NAP_) {
        const int r = tid - NUE_;
        const float4 x = *reinterpret_cast<const float4*>(x_ap + (size_t)r * 4);
        const float xv[4] = {x.x, x.y, x.z, x.w};
        for (int o = 0; o < OD_; ++o) {
          float a = c1_ew_b[o];
          #pragma unroll
          for (int k = 0; k < 4; ++k) a = fmaf(xv[k], c1_ew[(8 + k) * OD_ + o], a);
          Y1i[(size_t)r * OD_ + o] = a;
        }
      }
    }
    return;
  }
  const bool up = blockIdx.x < NB_;
  const int b = up ? blockIdx.x : blockIdx.x - NB_;
  const int NBINS = up ? NAP_ : NUE_;
  const int* dst = up ? up_dst : dn_dst;
  int* bh = up ? bh_up : bh_dn;
  unsigned short* lrank = up ? lr_up : lr_dn;
  for (int i = t; i < NBINS; i += 256) h[i] = 0;
  __syncthreads();
  const int base = b * CH_;
  #pragma unroll 1
  for (int i = t; i < CH_; i += 256)
    lrank[base + i] = (unsigned short)atomicAdd(&h[dst[base + i]], 1);
  __syncthreads();
  for (int i = t; i < NBINS; i += 256)
    bh[(size_t)i * NB_ + b] = h[i];
}

__global__ __launch_bounds__(64)
void bscanA2(int* __restrict__ bh_up, int* __restrict__ bh_dn,
             int* __restrict__ bs_up, int* __restrict__ bs_dn)
{
  const bool up = blockIdx.x < NAP_;
  const int bin = up ? blockIdx.x : blockIdx.x - NAP_;
  int* bh = up ? bh_up : bh_dn;
  int* binsum = up ? bs_up : bs_dn;
  const int l = threadIdx.x;
  int4 v = *reinterpret_cast<int4*>(&bh[(size_t)bin * NB_ + l * 4]);
  const int s0 = v.x, s1 = s0 + v.y, s2 = s1 + v.z, s3 = s2 + v.w;
  int inc = s3;
  #pragma unroll
  for (int d2 = 1; d2 < 64; d2 <<= 1) {
    int n = __shfl_up(inc, d2, 64);
    if (l >= d2) inc += n;
  }
  const int exc = inc - s3;
  int4 o; o.x = exc; o.y = exc + s0; o.z = exc + s1; o.w = exc + s2;
  *reinterpret_cast<int4*>(&bh[(size_t)bin * NB_ + l * 4]) = o;
  if (l == 63) binsum[bin] = inc;
}

__global__ __launch_bounds__(256)
void bscanB2(const int* __restrict__ bs_up, int* __restrict__ off_up,
             const int* __restrict__ bs_dn, int* __restrict__ off_dn)
{
  const bool up = blockIdx.x == 0;
  const int NBINS = up ? NAP_ : NUE_;
  const int K = NBINS / 256;
  const int* binsum = up ? bs_up : bs_dn;
  int* off = up ? off_up : off_dn;
  __shared__ int wtot[4];
  const int t = threadIdx.x, lane = t & 63, wid = t >> 6;
  int loc[4]; int s = 0;
  for (int k = 0; k < K; ++k) { loc[k] = binsum[t * K + k]; s += loc[k]; }
  int inc = s;
  #pragma unroll
  for (int d2 = 1; d2 < 64; d2 <<= 1) {
    int n = __shfl_up(inc, d2, 64);
    if (lane >= d2) inc += n;
  }
  if (lane == 63) wtot[wid] = inc;
  __syncthreads();
  int woff = 0;
  #pragma unroll
  for (int ww = 0; ww < 4; ++ww) if (ww < wid) woff += wtot[ww];
  int a = woff + inc - s;
  for (int k = 0; k < K; ++k) { off[t * K + k] = a; a += loc[k]; }
  if (t == 255) off[NBINS] = a;
}

__global__ __launch_bounds__(256)
void rankc2(const int* __restrict__ up_dst, const int* __restrict__ up_src,
            const int* __restrict__ dn_dst, const int* __restrict__ dn_src,
            const unsigned short* __restrict__ lr_up, const unsigned short* __restrict__ lr_dn,
            const int* __restrict__ bh_up, const int* __restrict__ bh_dn,
            const int* __restrict__ off_up, const int* __restrict__ off_dn,
            int* __restrict__ rank_dn,
            int* __restrict__ perm_up, int* __restrict__ srcP_up, int* __restrict__ dstP_up,
            int* __restrict__ perm_dn, int* __restrict__ srcP_dn, int* __restrict__ dstP_dn)
{
  const int gid = blockIdx.x * 256 + threadIdx.x;
  const bool up = gid < EN;
  const int e = up ? gid : gid - EN;
  const int* dst = up ? up_dst : dn_dst;
  const int* src = up ? up_src : dn_src;
  const unsigned short* lrank = up ? lr_up : lr_dn;
  const int* bh = up ? bh_up : bh_dn;
  const int* off = up ? off_up : off_dn;
  const int blk = e / CH_;
  const int d = dst[e];
  const int rk = off[d] + bh[(size_t)d * NB_ + blk] + (int)lrank[e];
  if (up) {
    perm_up[rk] = e; srcP_up[rk] = src[e]; dstP_up[rk] = d;
  } else {
    rank_dn[e] = rk;
    perm_dn[rk] = e; srcP_dn[rk] = src[e]; dstP_dn[rk] = d;
  }
}

// ---- fused conv1/conv2: edge stage + node update + next-conv tables ----
// Block = one dst node; streams its contiguous slot segment. 4 thr/edge.
__global__ __launch_bounds__(256)
void e12n(const float* __restrict__ ea_in,
          const int* __restrict__ perm, const int* __restrict__ srcP,
          const int* __restrict__ off,
          const float* __restrict__ Yje, const float* __restrict__ Yie,
          const float* __restrict__ Ym,
          const float* __restrict__ We,   // 4x60 (ea rows of ew_W)
          const float* __restrict__ Wm,   // 4x32
          unsigned short* __restrict__ outB,    // [E][64] bf16 mirror, slot order
          const float* __restrict__ x_in,       // [N][4]
          const float* __restrict__ W, const float* __restrict__ b,
          float* __restrict__ x_out,
          const float* __restrict__ WtA, float* __restrict__ YA,
          const float* __restrict__ WtB, const float* __restrict__ bB, float* __restrict__ YB,
          const float* __restrict__ WtC, const float* __restrict__ bC, float* __restrict__ YC)
{
  __shared__ unsigned short Eb[64 * 72];
  __shared__ float RedF[64][33];
  __shared__ float Part[8][33];
  __shared__ float Ag[32];
  __shared__ float Xr[4];
  __shared__ float Xn[OC_];
  const int d = blockIdx.x, t = threadIdx.x;
  const int beg = off[d], end = off[d + 1];
  const int r = t >> 2, j = t & 3;
  const int c0 = j * 15, m0 = j * 8;
  if (t < 4) Xr[t] = x_in[(size_t)d * 4 + t];
  float yie[15];
  #pragma unroll
  for (int c = 0; c < 15; ++c) yie[c] = Yie[(size_t)d * OD_ + c0 + c];
  float am[8] = {0.f, 0.f, 0.f, 0.f, 0.f, 0.f, 0.f, 0.f};

  for (int sb = beg; sb < end; sb += 64) {
    const int slot = sb + r;
    const bool act = slot < end;
    const int e = act ? perm[slot] : 0;
    const int s = act ? srcP[slot] : 0;
    float4 ea = act ? *reinterpret_cast<const float4*>(ea_in + (size_t)e * 4)
                    : make_float4(0.f, 0.f, 0.f, 0.f);
    const float eav[4] = {ea.x, ea.y, ea.z, ea.w};
    // ew cols [c0, c0+15)
    float acc[15];
    #pragma unroll
    for (int c = 0; c < 15; ++c) acc[c] = Yje[(size_t)s * OD_ + c0 + c] + yie[c];
    #pragma unroll
    for (int k = 0; k < 4; ++k)
      #pragma unroll
      for (int c = 0; c < 15; ++c)
        acc[c] = fmaf(eav[k], We[k * OD_ + c0 + c], acc[c]);
    if (act) {
      #pragma unroll
      for (int c = 0; c < 15; ++c) {
        float v = acc[c] >= 0.f ? acc[c] : 0.1f * acc[c];
        Eb[r * 72 + 4 + c0 + c] = f2bf(v);
      }
      if (j == 0) {
        Eb[r * 72 + 0] = f2bf(ea.x); Eb[r * 72 + 1] = f2bf(ea.y);
        Eb[r * 72 + 2] = f2bf(ea.z); Eb[r * 72 + 3] = f2bf(ea.w);
      }
    }
    // msg cols [m0, m0+8), accumulate in fp32 registers
    float m[8];
    #pragma unroll
    for (int c = 0; c < 8; ++c) m[c] = Ym[(size_t)s * HID_ + m0 + c];
    #pragma unroll
    for (int k = 0; k < 4; ++k)
      #pragma unroll
      for (int c = 0; c < 8; ++c)
        m[c] = fmaf(eav[k], Wm[k * HID_ + m0 + c], m[c]);
    if (act) {
      #pragma unroll
      for (int c = 0; c < 8; ++c)
        am[c] += m[c] >= 0.f ? m[c] : 0.1f * m[c];
    }
    __syncthreads();
    const int nact = end - sb < 64 ? end - sb : 64;
    for (int idx = t; idx < nact * 8; idx += 256) {
      int row = idx >> 3, ch = idx & 7;
      *reinterpret_cast<uint4*>(outB + (size_t)(sb + row) * OC_ + ch * 8) =
          *reinterpret_cast<const uint4*>(&Eb[row * 72 + ch * 8]);
    }
    __syncthreads();
  }
  // reduce am over the block: RedF[r][m0+c] -> Part[8][32] -> Ag[32]
  #pragma unroll
  for (int c = 0; c < 8; ++c) RedF[r][m0 + c] = am[c];
  __syncthreads();
  {
    const int col = t & 31, g = t >> 5;
    float s = 0.f;
    #pragma unroll
    for (int r2 = 0; r2 < 8; ++r2) s += RedF[g * 8 + r2][col];
    Part[g][col] = s;
  }
  __syncthreads();
  if (t < 32) {
    float s = 0.f;
    #pragma unroll
    for (int g2 = 0; g2 < 8; ++g2) s += Part[g2][t];
    Ag[t] = s;
  }
  __syncthreads();
  // node update (LX=4, no residual)
  if (t < OD_) {
    float acc = b[t];
    #pragma unroll
    for (int k = 0; k < 4; ++k) acc = fmaf(Xr[k], W[k * OD_ + t], acc);
    #pragma unroll 4
    for (int k = 0; k < HID_; ++k) acc = fmaf(Ag[k], W[(4 + k) * OD_ + t], acc);
    acc = acc >= 0.f ? acc : 0.1f * acc;
    x_out[(size_t)d * OC_ + 4 + t] = acc;
    Xn[4 + t] = acc;
  } else if (t < OC_) {
    x_out[(size_t)d * OC_ + (t - OD_)] = Xr[t - OD_];
    Xn[t - OD_] = Xr[t - OD_];
  }
  __syncthreads();
  if (t < OD_) {
    float a = 0.f;
    #pragma unroll 4
    for (int k = 0; k < OC_; ++k) a = fmaf(Xn[k], WtA[k * OD_ + t], a);
    YA[(size_t)d * OD_ + t] = a;
  } else if (t >= 64 && t < 96) {
    const int cc = t - 64;
    float a = bB[cc];
    #pragma unroll 4
    for (int k = 0; k < OC_; ++k) a = fmaf(Xn[k], WtB[k * HID_ + cc], a);
    YB[(size_t)d * HID_ + cc] = a;
  } else if (t >= 128 && t < 188) {
    const int cc = t - 128;
    float a = bC[cc];
    #pragma unroll 4
    for (int k = 0; k < OC_; ++k) a = fmaf(Xn[k], WtC[k * OD_ + cc], a);
    YC[(size_t)d * OD_ + cc] = a;
  }
}

// conv3 edge stage, slot order (r11-proven version: per-tile A loads,
// everything compile-time indexed — no scratch).
template<bool FUSE>
__global__ __launch_bounds__(256)
void edge3(const unsigned short* __restrict__ eaB,
           const float* __restrict__ ea0_src,
           const int* __restrict__ perm,
           const int* __restrict__ srcP, const int* __restrict__ dstP,
           const unsigned short* __restrict__ Wet, const unsigned short* __restrict__ Wmt,
           const float* __restrict__ Yje, const float* __restrict__ Yie,
           const float* __restrict__ Ym,
           unsigned int* __restrict__ msg32,
           float* __restrict__ ea_out,
           float* __restrict__ pT,
           const float* __restrict__ pe1_W)
{
  const int t = threadIdx.x, l = t & 63, w = t >> 6;
  const int lr = l & 15, lkb = l >> 4;
  const int sW = blockIdx.x * 256 + w * 64;

  bf16x8 be[4][2], bm[2][2];
  #pragma unroll
  for (int nt = 0; nt < 4; ++nt)
    #pragma unroll
    for (int kk = 0; kk < 2; ++kk)
      be[nt][kk] = *reinterpret_cast<const bf16x8*>(Wet + (nt * 16 + lr) * 64 + kk * 32 + lkb * 8);
  #pragma unroll
  for (int nt = 0; nt < 2; ++nt)
    #pragma unroll
    for (int kk = 0; kk < 2; ++kk)
      bm[nt][kk] = *reinterpret_cast<const bf16x8*>(Wmt + (nt * 16 + lr) * 64 + kk * 32 + lkb * 8);

  #pragma unroll 1
  for (int tile = 0; tile < 4; ++tile) {
    const int s0t = sW + tile * 16;
    const unsigned short* ar = eaB + (size_t)(s0t + lr) * OC_ + lkb * 8;
    bf16x8 a[2];
    a[0] = *reinterpret_cast<const bf16x8*>(ar);
    a[1] = *reinterpret_cast<const bf16x8*>(ar + 32);

    f32x4 accE[4] = {f32x4{0,0,0,0}, f32x4{0,0,0,0}, f32x4{0,0,0,0}, f32x4{0,0,0,0}};
    f32x4 accM[2] = {f32x4{0,0,0,0}, f32x4{0,0,0,0}};
    #pragma unroll
    for (int kk = 0; kk < 2; ++kk) {
      #pragma unroll
      for (int nt = 0; nt < 4; ++nt)
        accE[nt] = __builtin_amdgcn_mfma_f32_16x16x32_bf16(a[kk], be[nt][kk], accE[nt], 0, 0, 0);
      #pragma unroll
      for (int nt = 0; nt < 2; ++nt)
        accM[nt] = __builtin_amdgcn_mfma_f32_16x16x32_bf16(a[kk], bm[nt][kk], accM[nt], 0, 0, 0);
    }
    #pragma unroll
    for (int r = 0; r < 4; ++r) {
      const int sl = s0t + lkb * 4 + r;
      const int s = srcP[sl], d = dstP[sl];
      float v0 = accM[0][r] + Ym[(size_t)s * HID_ + lr];
      float v1 = accM[1][r] + Ym[(size_t)s * HID_ + 16 + lr];
      v0 = v0 >= 0.f ? v0 : 0.1f * v0;
      v1 = v1 >= 0.f ? v1 : 0.1f * v1;
      const int q0 = (2 * lr) & 15, q1 = (2 * lr + 1) & 15;
      float t00 = __shfl(v0, q0, 16), t10 = __shfl(v1, q0, 16);
      float t01 = __shfl(v0, q1, 16), t11 = __shfl(v1, q1, 16);
      float lo = (lr < 8) ? t00 : t10;
      float hi = (lr < 8) ? t01 : t11;
      msg32[(size_t)sl * 16 + lr] = ((unsigned)f2bf(hi) << 16) | f2bf(lo);

      float val[4];
      #pragma unroll
      for (int nt = 0; nt < 4; ++nt) {
        int col = nt * 16 + lr;
        float v = (col < OD_)
            ? accE[nt][r] + Yje[(size_t)s * OD_ + col] + Yie[(size_t)d * OD_ + col]
            : 0.f;
        val[nt] = v >= 0.f ? v : 0.1f * v;
      }
      if constexpr (!FUSE) {
        const int e = perm[sl];
        #pragma unroll
        for (int nt = 0; nt < 4; ++nt) {
          int col = nt * 16 + lr;
          if (col < OD_) ea_out[(size_t)e * OC_ + 4 + col] = val[nt];
        }
        if (lr == 0) {
          float4 ea0 = *reinterpret_cast<const float4*>(ea0_src + (size_t)e * 4);
          *reinterpret_cast<float4*>(ea_out + (size_t)e * OC_) = ea0;
        }
      } else {
        float p4[4] = {0.f, 0.f, 0.f, 0.f};
        #pragma unroll
        for (int nt = 0; nt < 4; ++nt) {
          int col = nt * 16 + lr;
          if (col < OD_) {
            #pragma unroll
            for (int jj = 0; jj < 4; ++jj)
              p4[jj] = fmaf(val[nt], pe1_W[(4 + col) * 4 + jj], p4[jj]);
          }
        }
        #pragma unroll
        for (int mk = 1; mk < 16; mk <<= 1) {
          #pragma unroll
          for (int jj = 0; jj < 4; ++jj)
            p4[jj] += __shfl_xor(p4[jj], mk, 64);
        }
        if (lr == 0)
          *reinterpret_cast<float4*>(pT + (size_t)sl * 4) =
              make_float4(p4[0], p4[1], p4[2], p4[3]);
      }
    }
  }
}

// ---- node update for conv3 (+ optional table build) ----
template<int LX, bool RES>
__device__ __forceinline__
void nodeup_body(int d, int t,
                 const float* __restrict__ x_in,
                 const unsigned int* __restrict__ msg32,
                 const int* __restrict__ off,
                 const float* __restrict__ W, const float* __restrict__ b,
                 float* __restrict__ x_out,
                 const float* WtA, float* YA,
                 const float* WtB, const float* bB, float* YB)
{
  __shared__ float Pb[16][32];
  __shared__ float Ag[32];
  __shared__ float Xr[LX];
  __shared__ float Xn[OC_];
  const int beg = off[d], end = off[d + 1];
  const int c = t & 15, g = t >> 4;
  float px = 0.f, py = 0.f;
  for (int i = beg + g; i < end; i += 16) {
    unsigned u = msg32[(size_t)i * 16 + c];
    px += bf2f(u & 0xffffu);
    py += bf2f(u >> 16);
  }
  Pb[g][2 * c] = px; Pb[g][2 * c + 1] = py;
  if (t < LX) Xr[t] = x_in[(size_t)d * LX + t];
  __syncthreads();
  if (t < 32) {
    float s = 0.f;
    #pragma unroll
    for (int g2 = 0; g2 < 16; ++g2) s += Pb[g2][t];
    Ag[t] = s;
  }
  __syncthreads();
  if (t < OD_) {
    float acc = b[t];
    #pragma unroll 4
    for (int k = 0; k < LX; ++k) acc = fmaf(Xr[k], W[k * OD_ + t], acc);
    #pragma unroll 4
    for (int k = 0; k < HID_; ++k) acc = fmaf(Ag[k], W[(LX + k) * OD_ + t], acc);
    acc = acc >= 0.f ? acc : 0.1f * acc;
    if constexpr (RES) acc += Xr[4 + t];
    x_out[(size_t)d * OC_ + 4 + t] = acc;
    Xn[4 + t] = acc;
  } else if (t < OC_) {
    x_out[(size_t)d * OC_ + (t - OD_)] = Xr[t - OD_];
    Xn[t - OD_] = Xr[t - OD_];
  }
  if (WtA == nullptr) return;
  __syncthreads();
  if (t < OD_) {
    float a = 0.f;
    #pragma unroll 4
    for (int k = 0; k < OC_; ++k) a = fmaf(Xn[k], WtA[k * OD_ + t], a);
    YA[(size_t)d * OD_ + t] = a;
  } else if (t >= 64 && t < 96) {
    const int cc = t - 64;
    float a = bB[cc];
    #pragma unroll 4
    for (int k = 0; k < OC_; ++k) a = fmaf(Xn[k], WtB[k * HID_ + cc], a);
    YB[(size_t)d * HID_ + cc] = a;
  }
}

template<int LX, bool RES>
__global__ __launch_bounds__(256)
void nodeupT(const float* __restrict__ x_in, const unsigned int* __restrict__ msg32,
             const int* __restrict__ off,
             const float* __restrict__ W, const float* __restrict__ b,
             float* __restrict__ x_out,
             const float* WtA, float* YA,
             const float* WtB, const float* bB, float* YB)
{
  nodeup_body<LX, RES>(blockIdx.x, threadIdx.x, x_in, msg32, off, W, b, x_out,
                       WtA, YA, WtB, bB, YB);
}

// final: nodeup(conv3d, UE) blocks [0,512) + powout blocks [512, 512+2048)
__global__ __launch_bounds__(256)
void nodeup_pow(const float* __restrict__ x_in, const unsigned int* __restrict__ msg32,
                const int* __restrict__ off,
                const float* __restrict__ W, const float* __restrict__ b,
                float* __restrict__ x_out,
                const float* __restrict__ ea0_src, const int* __restrict__ rank,
                const float* __restrict__ pT,
                const float* __restrict__ pe1_W, const float* __restrict__ pe1_b,
                const float* __restrict__ pe2_W, const float* __restrict__ pe2_b,
                const float* __restrict__ ln_g, const float* __restrict__ ln_b,
                float* __restrict__ outp)
{
  if (blockIdx.x < NUE_) {
    nodeup_body<OC_, true>(blockIdx.x, threadIdx.x, x_in, msg32, off, W, b, x_out,
                           nullptr, nullptr, nullptr, nullptr, nullptr);
    return;
  }
  const int e = (blockIdx.x - NUE_) * 256 + threadIdx.x;
  const int rk = rank[e];
  const float4 p4 = *reinterpret_cast<const float4*>(pT + (size_t)rk * 4);
  const float4 ea0 = *reinterpret_cast<const float4*>(ea0_src + (size_t)e * 4);
  const float pv[4] = {p4.x, p4.y, p4.z, p4.w};
  float v4[4];
  #pragma unroll
  for (int jj = 0; jj < 4; ++jj)
    v4[jj] = pv[jj] + pe1_b[jj]
           + ea0.x * pe1_W[0 * 4 + jj] + ea0.y * pe1_W[1 * 4 + jj]
           + ea0.z * pe1_W[2 * 4 + jj] + ea0.w * pe1_W[3 * 4 + jj];
  const float mu = 0.25f * (v4[0] + v4[1] + v4[2] + v4[3]);
  float var = 0.f;
  #pragma unroll
  for (int jj = 0; jj < 4; ++jj) { float dd = v4[jj] - mu; var = fmaf(dd, dd, var); }
  var *= 0.25f;
  const float rstd = rsqrtf(var + 1e-5f);
  float p = pe2_b[0];
  #pragma unroll
  for (int jj = 0; jj < 4; ++jj) {
    float h = (v4[jj] - mu) * rstd * ln_g[jj] + ln_b[jj];
    h = h >= 0.f ? h : 0.1f * h;
    p = fmaf(h, pe2_W[jj], p);
  }
  float* orow = outp + (size_t)e * 5;
  orow[0] = ea0.x; orow[1] = ea0.y; orow[2] = ea0.z; orow[3] = ea0.w;
  orow[4] = p;
}

extern "C" void kernel_launch(void* const* d_in, const int* in_sizes, int n_in,
                              void* d_out, int out_size, void* d_ws, size_t ws_size,
                              hipStream_t stream)
{
  const float* x_ue    = (const float*)d_in[0];
  const float* x_ap    = (const float*)d_in[1];
  const float* ea_up   = (const float*)d_in[2];
  const float* ea_down = (const float*)d_in[3];
  const int* up_src = (const int*)d_in[4];
  const int* up_dst = (const int*)d_in[5];
  const int* dn_src = (const int*)d_in[6];
  const int* dn_dst = (const int*)d_in[7];
  const float* c1_msg_W = (const float*)d_in[8];  const float* c1_msg_b = (const float*)d_in[9];
  const float* c1_upd_W = (const float*)d_in[10]; const float* c1_upd_b = (const float*)d_in[11];
  const float* c1_ew_W  = (const float*)d_in[12]; const float* c1_ew_b  = (const float*)d_in[13];
  const float* c2_msg_W = (const float*)d_in[14]; const float* c2_msg_b = (const float*)d_in[15];
  const float* c2_upd_W = (const float*)d_in[16]; const float* c2_upd_b = (const float*)d_in[17];
  const float* c2_ew_W  = (const float*)d_in[18]; const float* c2_ew_b  = (const float*)d_in[19];
  const float* c3u_msg_W= (const float*)d_in[20]; const float* c3u_msg_b= (const float*)d_in[21];
  const float* c3u_upd_W= (const float*)d_in[22]; const float* c3u_upd_b= (const float*)d_in[23];
  const float* c3u_ew_W = (const float*)d_in[24]; const float* c3u_ew_b = (const float*)d_in[25];
  const float* c3d_msg_W= (const float*)d_in[26]; const float* c3d_msg_b= (const float*)d_in[27];
  const float* c3d_upd_W= (const float*)d_in[28]; const float* c3d_upd_b= (const float*)d_in[29];
  const float* c3d_ew_W = (const float*)d_in[30]; const float* c3d_ew_b = (const float*)d_in[31];
  const float* pe1_W = (const float*)d_in[32]; const float* pe1_b = (const float*)d_in[33];
  const float* pe2_W = (const float*)d_in[34]; const float* pe2_b = (const float*)d_in[35];
  const float* ln_g  = (const float*)d_in[36]; const float* ln_b  = (const float*)d_in[37];

  float* out    = (float*)d_out;
  float* x_ue_o = out;
  float* x_ap_o = out + (size_t)NUE_ * OC_;
  float* ea_up_o = x_ap_o + (size_t)NAP_ * OC_;
  float* ea_dn_o = ea_up_o + (size_t)EN * OC_;

  // ---- workspace layout ----
  int* ip = (int*)d_ws;
  int* rank_dn = ip; ip += EN;
  int* perm_up = ip; ip += EN;
  int* src_upP = ip; ip += EN;
  int* dst_upP = ip; ip += EN;
  int* perm_dn = ip; ip += EN;
  int* src_dnP = ip; ip += EN;
  int* dst_dnP = ip; ip += EN;
  int* bh_up   = ip; ip += NAP_ * NB_;
  int* bh_dn   = ip; ip += NUE_ * NB_;
  int* off_up  = ip; ip += NAP_ + 1;
  int* off_dn  = ip; ip += NUE_ + 1;
  int* bs_up   = ip; ip += NAP_;
  int* bs_dn   = ip; ip += NUE_;
  unsigned short* lr_up = (unsigned short*)ip; ip += EN / 2;
  unsigned short* lr_dn = (unsigned short*)ip; ip += EN / 2;
  float* p = (float*)ip;
  float* Y1j = p;  p += NUE_ * OD_;  float* Y1i = p; p += NAP_ * OD_;  float* Y1m = p; p += NUE_ * HID_;
  float* Y2j = p;  p += NAP_ * OD_;  float* Y2i = p; p += NUE_ * OD_;  float* Y2m = p; p += NAP_ * HID_;
  float* Y3uj = p; p += NUE_ * OD_;  float* Y3ui = p; p += NAP_ * OD_; float* Y3um = p; p += NUE_ * HID_;
  float* Y3dj = p; p += NAP_ * OD_;  float* Y3di = p; p += NUE_ * OD_; float* Y3dm = p; p += NAP_ * HID_;
  float* pT = p;   p += (size_t)EN * 4;
  unsigned short* us = (unsigned short*)p;
  unsigned short* ea_up_bf = us;  us += (size_t)EN * OC_;
  unsigned short* ea_dn_bf = us;  us += (size_t)EN * OC_;
  unsigned short* we3u = us; us += 64 * 64;
  unsigned short* wm3u = us; us += 32 * 64;
  unsigned short* we3d = us; us += 64 * 64;
  unsigned short* wm3d = us; us += 32 * 64;
  unsigned int* msg32 = (unsigned int*)(((size_t)us + 15) & ~(size_t)15);

  const dim3 blk(256);
  const dim3 ege(EN / 256);        // 2048

  // phase 1: histograms + (folded) weight prep + input tables
  lhist2x<<<dim3(2 * NB_ + 56), blk, 0, stream>>>(
      up_dst, dn_dst, bh_up, bh_dn, lr_up, lr_dn,
      c3u_ew_W, c3u_msg_W, c3d_ew_W, c3d_msg_W, we3u, wm3u, we3d, wm3d,
      x_ue, x_ap, c1_ew_W, c1_msg_W, c1_ew_b, c1_msg_b, c2_ew_W, c2_ew_b,
      Y1j, Y1i, Y1m, Y2i);
  bscanA2<<<dim3(NAP_ + NUE_), dim3(64), 0, stream>>>(bh_up, bh_dn, bs_up, bs_dn);
  bscanB2<<<dim3(2), blk, 0, stream>>>(bs_up, off_up, bs_dn, off_dn);
  rankc2<<<dim3(2 * EN / 256), blk, 0, stream>>>(
      up_dst, up_src, dn_dst, dn_src, lr_up, lr_dn, bh_up, bh_dn, off_up, off_dn,
      rank_dn, perm_up, src_upP, dst_upP, perm_dn, src_dnP, dst_dnP);

  // conv1 (fused edge+node): builds Y2j/Y2m + Y3ui
  e12n<<<dim3(NAP_), blk, 0, stream>>>(
      ea_up, perm_up, src_upP, off_up, Y1j, Y1i, Y1m,
      c1_ew_W + 4 * OD_, c1_msg_W + 4 * HID_, ea_up_bf,
      x_ap, c1_upd_W, c1_upd_b, x_ap_o,
      c2_ew_W, Y2j, c2_msg_W, c2_msg_b, Y2m,
      c3u_ew_W + 128 * OD_, c3u_ew_b, Y3ui);

  // conv2 (fused edge+node): builds Y3uj/Y3um + Y3di
  e12n<<<dim3(NUE_), blk, 0, stream>>>(
      ea_down, perm_dn, src_dnP, off_dn, Y2j, Y2i, Y2m,
      c2_ew_W + 64 * OD_, c2_msg_W + 64 * HID_, ea_dn_bf,
      x_ue, c2_upd_W, c2_upd_b, x_ue_o,
      c3u_ew_W, Y3uj, c3u_msg_W, c3u_msg_b, Y3um,
      c3d_ew_W + 128 * OD_, c3d_ew_b, Y3di);

  // conv3u: edge GEMM then node update (+Y3dj/Y3dm tables)
  edge3<false><<<ege, blk, 0, stream>>>(
      ea_up_bf, ea_up, perm_up, src_upP, dst_upP, we3u, wm3u,
      Y3uj, Y3ui, Y3um, msg32, ea_up_o, nullptr, nullptr);
  nodeupT<64, true><<<dim3(NAP_), blk, 0, stream>>>(
      x_ap_o, msg32, off_up, c3u_upd_W, c3u_upd_b, x_ap_o,
      c3d_ew_W, Y3dj, c3d_msg_W, c3d_msg_b, Y3dm);

  // conv3d: edge GEMM -> pT, then merged nodeup+powout
  edge3<true><<<ege, blk, 0, stream>>>(
      ea_dn_bf, nullptr, nullptr, src_dnP, dst_dnP, we3d, wm3d,
      Y3dj, Y3di, Y3dm, msg32, nullptr, pT, pe1_W);
  nodeup_pow<<<dim3(NUE_ + EN / 256), blk, 0, stream>>>(
      x_ue_o, msg32, off_dn, c3d_upd_W, c3d_upd_b, x_ue_o,
      ea_down, rank_dn, pT, pe1_W, pe1_b, pe2_W, pe2_b, ln_g, ln_b, ea_dn_o);
}